// Round 1
// baseline (214.380 us; speedup 1.0000x reference)
//
#include <hip/hip_runtime.h>

namespace {

constexpr int kB = 4;
constexpr int kT = 512;
constexpr int kH = 256;

// tanh(q+k) where a2 = 2*(q+k) is precomputed: tanh = 1 - 2/(exp(a2)+1)
__device__ __forceinline__ float tanh_pre(float a2) {
  float e = __expf(a2);                         // v_mul + v_exp_f32
  float r = __builtin_amdgcn_rcpf(e + 1.0f);    // v_rcp_f32
  return __builtin_fmaf(-2.0f, r, 1.0f);
}

// ---------------- K1: Q = 2*(X @ W1^T), K = 2*(X @ W2^T) ----------------
__global__ __launch_bounds__(256) void proj_kernel(
    const float* __restrict__ X, const float* __restrict__ W1,
    const float* __restrict__ W2, float* __restrict__ Qc,
    float* __restrict__ Kc) {
  __shared__ __align__(16) float xs[16][kH];
  const int row0 = blockIdx.x * 16;
  const int tid = threadIdx.x;
  const float* W = (blockIdx.y == 0) ? W1 : W2;
  float* out = (blockIdx.y == 0) ? Qc : Kc;

#pragma unroll
  for (int i = 0; i < 16; ++i)
    xs[i][tid] = X[(size_t)(row0 + i) * kH + tid];
  __syncthreads();

  const float4* Wrow = reinterpret_cast<const float4*>(W + (size_t)tid * kH);
  float acc[16];
#pragma unroll
  for (int i = 0; i < 16; ++i) acc[i] = 0.0f;

  for (int j4 = 0; j4 < kH / 4; ++j4) {
    const float4 w = Wrow[j4];
#pragma unroll
    for (int i = 0; i < 16; ++i) {
      const float4 x = *reinterpret_cast<const float4*>(&xs[i][j4 * 4]);
      acc[i] = __builtin_fmaf(w.x, x.x, acc[i]);
      acc[i] = __builtin_fmaf(w.y, x.y, acc[i]);
      acc[i] = __builtin_fmaf(w.z, x.z, acc[i]);
      acc[i] = __builtin_fmaf(w.w, x.w, acc[i]);
    }
  }
#pragma unroll
  for (int i = 0; i < 16; ++i)
    out[(size_t)(row0 + i) * kH + tid] = acc[i] * 2.0f;
}

// ---------------- K2: scores -> softmax -> weights + context ----------------
// Block handles 4 t-rows {511-g, 256+g, 255-g, g} (descending) for batch b.
// Sum of (t+1) is constant (1026) -> perfectly balanced blocks.

template <int NK>
__device__ __forceinline__ void score_rows(const float4* __restrict__ Krow,
                                           float (*qs)[kH],
                                           const float* __restrict__ vs,
                                           float* acc) {
  for (int j4 = 0; j4 < kH / 4; ++j4) {
    const float4 kv = Krow[j4];
    const float4 vv = *reinterpret_cast<const float4*>(&vs[j4 * 4]);
#pragma unroll
    for (int k = 0; k < NK; ++k) {
      const float4 qv = *reinterpret_cast<const float4*>(&qs[k][j4 * 4]);
      acc[k] = __builtin_fmaf(vv.x, tanh_pre(qv.x + kv.x), acc[k]);
      acc[k] = __builtin_fmaf(vv.y, tanh_pre(qv.y + kv.y), acc[k]);
      acc[k] = __builtin_fmaf(vv.z, tanh_pre(qv.z + kv.z), acc[k]);
      acc[k] = __builtin_fmaf(vv.w, tanh_pre(qv.w + kv.w), acc[k]);
    }
  }
}

__global__ __launch_bounds__(256, 2) void attn_kernel(
    const float* __restrict__ X, const float* __restrict__ Qc,
    const float* __restrict__ Kc, const float* __restrict__ v,
    float* __restrict__ ctx, float* __restrict__ wout) {
  __shared__ __align__(16) float qs[4][kH];
  __shared__ __align__(16) float vs[kH];
  __shared__ __align__(16) float sc[4][kT];
  __shared__ float red[4];

  const int g = blockIdx.x;   // 0..127
  const int b = blockIdx.y;   // 0..3
  const int tid = threadIdx.x;
  const int tt0 = 511 - g, tt1 = 256 + g, tt2 = 255 - g, tt3 = g;
  const int tt[4] = {tt0, tt1, tt2, tt3};

  vs[tid] = v[tid];
#pragma unroll
  for (int k = 0; k < 4; ++k)
    qs[k][tid] = Qc[(size_t)(b * kT + tt[k]) * kH + tid];
  __syncthreads();

  // ---- scores: thread owns source position s; K row streamed once ----
#pragma unroll
  for (int c = 0; c < 2; ++c) {
    const int s = c * 256 + tid;
    if (s <= tt0) {
      const float4* Krow =
          reinterpret_cast<const float4*>(Kc + (size_t)(b * kT + s) * kH);
      float acc[4] = {0.f, 0.f, 0.f, 0.f};
      if (s <= tt3)       score_rows<4>(Krow, qs, vs, acc);
      else if (s <= tt2)  score_rows<3>(Krow, qs, vs, acc);
      else if (s <= tt1)  score_rows<2>(Krow, qs, vs, acc);
      else                score_rows<1>(Krow, qs, vs, acc);
      sc[0][s] = acc[0];
      if (s <= tt1) sc[1][s] = acc[1];
      if (s <= tt2) sc[2][s] = acc[2];
      if (s <= tt3) sc[3][s] = acc[3];
    }
  }
  __syncthreads();

  // ---- softmax (|score| <= sum|v| ~= 13, no max-subtraction needed) ----
  float wlo[4], whi[4];
#pragma unroll
  for (int k = 0; k < 4; ++k) {
    const int t = tt[k];
    const float p1 = (tid <= t) ? __expf(sc[k][tid]) : 0.0f;
    const float p2 = (tid + 256 <= t) ? __expf(sc[k][tid + 256]) : 0.0f;
    float local = p1 + p2;
#pragma unroll
    for (int off = 32; off > 0; off >>= 1)
      local += __shfl_xor(local, off, 64);
    if ((tid & 63) == 0) red[tid >> 6] = local;
    __syncthreads();
    const float sum = red[0] + red[1] + red[2] + red[3];
    __syncthreads();  // red[] reused next k
    const float rs = __builtin_amdgcn_rcpf(sum);
    wlo[k] = p1 * rs;
    whi[k] = p2 * rs;
  }

  // ---- write weights (zeros beyond t) and stash weights back into sc ----
#pragma unroll
  for (int k = 0; k < 4; ++k) {
    sc[k][tid] = wlo[k];
    sc[k][tid + 256] = whi[k];
    float* wrow = wout + ((size_t)(b * kT + tt[k])) * kT;
    wrow[tid] = wlo[k];
    wrow[tid + 256] = whi[k];
  }
  __syncthreads();

  // ---- context: thread owns column h = tid; segmented causal loops ----
  const float* Xb = X + (size_t)b * kT * kH;
  float a0 = 0.f, a1 = 0.f, a2 = 0.f, a3 = 0.f;
  int s = 0;
  for (; s <= tt3; ++s) {  // all 4 rows active
    const float x = Xb[(size_t)s * kH + tid];
    a0 = __builtin_fmaf(sc[0][s], x, a0);
    a1 = __builtin_fmaf(sc[1][s], x, a1);
    a2 = __builtin_fmaf(sc[2][s], x, a2);
    a3 = __builtin_fmaf(sc[3][s], x, a3);
  }
  for (; s <= tt2; ++s) {
    const float x = Xb[(size_t)s * kH + tid];
    a0 = __builtin_fmaf(sc[0][s], x, a0);
    a1 = __builtin_fmaf(sc[1][s], x, a1);
    a2 = __builtin_fmaf(sc[2][s], x, a2);
  }
  for (; s <= tt1; ++s) {
    const float x = Xb[(size_t)s * kH + tid];
    a0 = __builtin_fmaf(sc[0][s], x, a0);
    a1 = __builtin_fmaf(sc[1][s], x, a1);
  }
  for (; s <= tt0; ++s) {
    const float x = Xb[(size_t)s * kH + tid];
    a0 = __builtin_fmaf(sc[0][s], x, a0);
  }
  ctx[(size_t)(b * kT + tt0) * kH + tid] = a0;
  ctx[(size_t)(b * kT + tt1) * kH + tid] = a1;
  ctx[(size_t)(b * kT + tt2) * kH + tid] = a2;
  ctx[(size_t)(b * kT + tt3) * kH + tid] = a3;
}

}  // namespace

extern "C" void kernel_launch(void* const* d_in, const int* in_sizes, int n_in,
                              void* d_out, int out_size, void* d_ws,
                              size_t ws_size, hipStream_t stream) {
  const float* X = (const float*)d_in[0];
  const float* W1 = (const float*)d_in[1];
  const float* W2 = (const float*)d_in[2];
  const float* v = (const float*)d_in[3];

  float* ctx = (float*)d_out;                        // B*T*H
  float* wout = ctx + (size_t)kB * kT * kH;          // B*T*T
  float* Qc = (float*)d_ws;                          // B*T*H (scaled by 2)
  float* Kc = Qc + (size_t)kB * kT * kH;             // B*T*H (scaled by 2)

  proj_kernel<<<dim3(kB * kT / 16, 2), 256, 0, stream>>>(X, W1, W2, Qc, Kc);
  attn_kernel<<<dim3(kT / 4, kB), 256, 0, stream>>>(X, Qc, Kc, v, ctx, wout);
}

// Round 2
// 109.778 us; speedup vs baseline: 1.9529x; 1.9529x over previous
//
#include <hip/hip_runtime.h>

namespace {

constexpr int kB = 4;
constexpr int kT = 512;
constexpr int kH = 256;

__device__ __forceinline__ float rcpf(float x) {
  return __builtin_amdgcn_rcpf(x);
}

// ---------------- k0: transpose W1,W2 (H x H, row-major) into Wt ----------------
__global__ __launch_bounds__(256) void transpose_w_kernel(
    const float* __restrict__ W1, const float* __restrict__ W2,
    float* __restrict__ Wt1, float* __restrict__ Wt2) {
  __shared__ float tile[32][33];
  const float* Win = (blockIdx.z == 0) ? W1 : W2;
  float* Wout = (blockIdx.z == 0) ? Wt1 : Wt2;
  const int jo = blockIdx.x * 32, ho = blockIdx.y * 32;
  const int c = threadIdx.x & 31, r0 = threadIdx.x >> 5;  // 8 rows/pass
#pragma unroll
  for (int p = 0; p < 4; ++p)
    tile[r0 + 8 * p][c] = Win[(size_t)(ho + r0 + 8 * p) * kH + jo + c];
  __syncthreads();
#pragma unroll
  for (int p = 0; p < 4; ++p)
    Wout[(size_t)(jo + r0 + 8 * p) * kH + ho + c] = tile[c][r0 + 8 * p];
}

// ---------------- k1: projections + exp + layout ----------------
// y==0: EQA[row][h] = exp(2*(X@W1^T)) / v[h]        (row-major [2048][256])
// y==1: EKt[b*256+h][s] = exp(2*(X@W2^T))           (transposed [1024][512])
__global__ __launch_bounds__(256) void proj_kernel(
    const float* __restrict__ X, const float* __restrict__ Wt1,
    const float* __restrict__ Wt2, const float* __restrict__ v,
    float* __restrict__ EQA, float* __restrict__ EKt) {
  __shared__ float tl[kH][9];
  const int tid = threadIdx.x;  // h
  const int row0 = blockIdx.x * 8;
  const float* Wt = (blockIdx.y == 0) ? Wt1 : Wt2;

  float acc[8];
#pragma unroll
  for (int i = 0; i < 8; ++i) acc[i] = 0.0f;

  for (int j0 = 0; j0 < kH; j0 += 8) {
    float wv[8];
#pragma unroll
    for (int u = 0; u < 8; ++u) wv[u] = Wt[(size_t)(j0 + u) * kH + tid];
#pragma unroll
    for (int i = 0; i < 8; ++i) {
      const float* xr = X + (size_t)(row0 + i) * kH;  // uniform -> s_load
#pragma unroll
      for (int u = 0; u < 8; ++u)
        acc[i] = __builtin_fmaf(xr[j0 + u], wv[u], acc[i]);
    }
  }

  if (blockIdx.y == 0) {
    const float rv = 1.0f / v[tid];
#pragma unroll
    for (int i = 0; i < 8; ++i)
      EQA[(size_t)(row0 + i) * kH + tid] = __expf(2.0f * acc[i]) * rv;
  } else {
#pragma unroll
    for (int i = 0; i < 8; ++i) tl[tid][i] = __expf(2.0f * acc[i]);
    __syncthreads();
    const int bb = row0 >> 9, s0 = row0 & (kT - 1);
    float* out = EKt + ((size_t)(bb * kH + tid)) * kT + s0;
    float4 lo = {tl[tid][0], tl[tid][1], tl[tid][2], tl[tid][3]};
    float4 hi = {tl[tid][4], tl[tid][5], tl[tid][6], tl[tid][7]};
    *reinterpret_cast<float4*>(out) = lo;
    *reinterpret_cast<float4*>(out + 4) = hi;
  }
}

// ---------------- k2: scores -> softmax -> weights + context ----------------
// Block: 512 threads, batch b, 4 t-rows {511-g, 256+g, 255-g, g}; thread owns s=tid.
// score[t][s] = vsum - 2 * sum_h rcp( EQA[t][h]*EKt[h][s] + 1/v[h] )

template <int NK>
__device__ __forceinline__ void score_loop(const float* __restrict__ ekp,
                                           const float (*eqa)[kH],
                                           const float* __restrict__ rvl,
                                           float* acc) {
#pragma unroll 2
  for (int h0 = 0; h0 < kH; h0 += 8) {
    float ek[8];
#pragma unroll
    for (int u = 0; u < 8; ++u) ek[u] = ekp[(size_t)(h0 + u) * kT];
    const float4 rva = *reinterpret_cast<const float4*>(&rvl[h0]);
    const float4 rvb = *reinterpret_cast<const float4*>(&rvl[h0 + 4]);
#pragma unroll
    for (int k = 0; k < NK; ++k) {
      const float4 ea = *reinterpret_cast<const float4*>(&eqa[k][h0]);
      const float4 eb = *reinterpret_cast<const float4*>(&eqa[k][h0 + 4]);
      const float r0 = rcpf(__builtin_fmaf(ea.x, ek[0], rva.x));
      const float r1 = rcpf(__builtin_fmaf(ea.y, ek[1], rva.y));
      const float r2 = rcpf(__builtin_fmaf(ea.z, ek[2], rva.z));
      const float r3 = rcpf(__builtin_fmaf(ea.w, ek[3], rva.w));
      const float r4 = rcpf(__builtin_fmaf(eb.x, ek[4], rvb.x));
      const float r5 = rcpf(__builtin_fmaf(eb.y, ek[5], rvb.y));
      const float r6 = rcpf(__builtin_fmaf(eb.z, ek[6], rvb.z));
      const float r7 = rcpf(__builtin_fmaf(eb.w, ek[7], rvb.w));
      acc[k] += ((r0 + r1) + (r2 + r3)) + ((r4 + r5) + (r6 + r7));
    }
  }
}

__global__ __launch_bounds__(512, 4) void attn_kernel(
    const float* __restrict__ X, const float* __restrict__ EQA,
    const float* __restrict__ EKt, const float* __restrict__ v,
    float* __restrict__ ctx, float* __restrict__ wout) {
  __shared__ __align__(16) float eqa[4][kH];
  __shared__ __align__(16) float rvl[kH];
  __shared__ __align__(16) float sc[4][kT];
  __shared__ float redm[8][4];
  __shared__ float redv[4];

  const int g = blockIdx.x;   // 0..127
  const int b = blockIdx.y;   // 0..3
  const int tid = threadIdx.x;
  const int tt0 = 511 - g, tt1 = 256 + g, tt2 = 255 - g, tt3 = g;

  // ---- stage: eqa rows, rv table, vsum ----
  if (tid < kH) {
    const int tt[4] = {tt0, tt1, tt2, tt3};
#pragma unroll
    for (int k = 0; k < 4; ++k)
      eqa[k][tid] = EQA[(size_t)(b * kT + tt[k]) * kH + tid];
    float vv = v[tid];
    rvl[tid] = 1.0f / vv;
#pragma unroll
    for (int off = 32; off > 0; off >>= 1) vv += __shfl_xor(vv, off, 64);
    if ((tid & 63) == 0) redv[tid >> 6] = vv;
  }
  __syncthreads();
  const float vsum = redv[0] + redv[1] + redv[2] + redv[3];

  // ---- scores ----
  const int s = tid;
  {
    const float* ekp = EKt + ((size_t)b * kH) * kT + s;
    float acc[4] = {0.f, 0.f, 0.f, 0.f};
    if (s <= tt3) {
      score_loop<4>(ekp, eqa, rvl, acc);
    } else if (s <= tt2) {
      score_loop<3>(ekp, eqa, rvl, acc);
    } else if (s <= tt1) {
      score_loop<2>(ekp, eqa, rvl, acc);
    } else {
      score_loop<1>(ekp, eqa, rvl, acc);
    }
    sc[0][s] = __builtin_fmaf(-2.0f, acc[0], vsum);
    if (s <= tt1) sc[1][s] = __builtin_fmaf(-2.0f, acc[1], vsum);
    if (s <= tt2) sc[2][s] = __builtin_fmaf(-2.0f, acc[2], vsum);
    if (s <= tt3) sc[3][s] = __builtin_fmaf(-2.0f, acc[3], vsum);
  }
  __syncthreads();

  // ---- softmax over s for each of the 4 rows ----
  const int tt[4] = {tt0, tt1, tt2, tt3};
  float p[4];
#pragma unroll
  for (int k = 0; k < 4; ++k) {
    p[k] = (tid <= tt[k]) ? __expf(sc[k][tid]) : 0.0f;
    float l = p[k];
#pragma unroll
    for (int off = 32; off > 0; off >>= 1) l += __shfl_xor(l, off, 64);
    if ((tid & 63) == 0) redm[tid >> 6][k] = l;
  }
  __syncthreads();
#pragma unroll
  for (int k = 0; k < 4; ++k) {
    float sum = 0.f;
#pragma unroll
    for (int w = 0; w < 8; ++w) sum += redm[w][k];
    const float wgt = p[k] * rcpf(sum);
    wout[(size_t)(b * kT + tt[k]) * kT + tid] = wgt;
    sc[k][tid] = wgt;  // own column only -> no cross-thread hazard
  }
  __syncthreads();

  // ---- context: halves {rows tt0,tt3} / {rows tt1,tt2}, thread owns h ----
  const int half = tid >> 8;
  const int h = tid & (kH - 1);
  const int longT = half ? tt1 : tt0;
  const int shortT = half ? tt2 : tt3;
  const float* wL = half ? &sc[1][0] : &sc[0][0];
  const float* wS = half ? &sc[2][0] : &sc[3][0];
  const float* Xb = X + ((size_t)b * kT) * kH + h;

  float aL = 0.f, aS = 0.f;
  int si = 0;
#pragma unroll 4
  for (; si <= shortT; ++si) {
    const float x = Xb[(size_t)si * kH];
    aL = __builtin_fmaf(wL[si], x, aL);
    aS = __builtin_fmaf(wS[si], x, aS);
  }
#pragma unroll 4
  for (; si <= longT; ++si) {
    const float x = Xb[(size_t)si * kH];
    aL = __builtin_fmaf(wL[si], x, aL);
  }
  ctx[(size_t)(b * kT + longT) * kH + h] = aL;
  ctx[(size_t)(b * kT + shortT) * kH + h] = aS;
}

}  // namespace

extern "C" void kernel_launch(void* const* d_in, const int* in_sizes, int n_in,
                              void* d_out, int out_size, void* d_ws,
                              size_t ws_size, hipStream_t stream) {
  const float* X = (const float*)d_in[0];
  const float* W1 = (const float*)d_in[1];
  const float* W2 = (const float*)d_in[2];
  const float* v = (const float*)d_in[3];

  float* ctx = (float*)d_out;                       // [B*T][H]   2 MB
  float* wout = ctx + (size_t)kB * kT * kH;         // [B*T][T]   4 MB
  // scratch: Wt tables live in the weights region (fully overwritten by attn)
  float* Wt1 = wout;                                // 256 KB
  float* Wt2 = wout + (size_t)kH * kH;              // 256 KB
  float* EQA = (float*)d_ws;                        // [B*T][H]   2 MB
  float* EKt = EQA + (size_t)kB * kT * kH;          // [B*H][T]   2 MB

  transpose_w_kernel<<<dim3(8, 8, 2), 256, 0, stream>>>(W1, W2, Wt1, Wt2);
  proj_kernel<<<dim3(kB * kT / 8, 2), 256, 0, stream>>>(X, Wt1, Wt2, v, EQA, EKt);
  attn_kernel<<<dim3(kT / 4, kB), 512, 0, stream>>>(X, EQA, EKt, v, ctx, wout);
}